// Round 6
// baseline (970.133 us; speedup 1.0000x reference)
//
#include <hip/hip_runtime.h>
#include <math.h>

#define NF 128   // feature width (both in and out of every layer)

typedef int      vint4   __attribute__((ext_vector_type(4)));
typedef float    vfloat4 __attribute__((ext_vector_type(4)));
typedef _Float16 vhalf4  __attribute__((ext_vector_type(4)));

// ---------------------------------------------------------------------------
// Precompute kernels: degree count, dinv + CSR offset allocation, CSR fill
// CSR stores ONLY the src index (4 B/edge): the edge weight dinv[r]*dinv[c]
// is algebraically folded into the GEMM epilogue (tmp' = dinv*tmp) and the
// aggregation epilogue (scale by dinv[v]). This halves k_fill's scattered
// write traffic (round-5 profile: 8x XCD write amplification, 200 MB HBM).
// ---------------------------------------------------------------------------
__global__ __launch_bounds__(256) void k_count(const int* __restrict__ col,
                                               int* __restrict__ cnt, int E) {
  int i = blockIdx.x * blockDim.x + threadIdx.x;
  if (i < E) atomicAdd(&cnt[col[i]], 1);
}

__global__ __launch_bounds__(256) void k_nodeinit(const int* __restrict__ cnt,
                                                  float* __restrict__ dinv,
                                                  int* __restrict__ offs,
                                                  int* __restrict__ cursor,
                                                  int* __restrict__ total, int N) {
  int i = blockIdx.x * blockDim.x + threadIdx.x;
  if (i < N) {
    int c = cnt[i];
    // deg = (#incoming edges) + FILL(2.0) from the self-loop; always > 0
    dinv[i] = rsqrtf((float)c + 2.0f);
    int o = atomicAdd(total, c);   // segment placement order is irrelevant (sum)
    offs[i] = o;
    cursor[i] = o;
  }
}

__global__ __launch_bounds__(256) void k_fill(const int* __restrict__ row,
                                              const int* __restrict__ col,
                                              int* __restrict__ cursor,
                                              int* __restrict__ csr, int E) {
  int i = blockIdx.x * blockDim.x + threadIdx.x;
  if (i < E) {
    int r = row[i], c = col[i];
    int p = atomicAdd(&cursor[c], 1);
    csr[p] = r;
  }
}

// ---------------------------------------------------------------------------
// GEMM: out[N,128] = dinv[row] * (H[N,128] @ W[128,128])  (f32 FMA, fp16 out)
// Tile 64 rows x 128 cols per block, BK=32 K-chunks.
// 256 threads; thread = 8 rows x 4 cols.
// ---------------------------------------------------------------------------
#define BM 64
#define BK 32
__global__ __launch_bounds__(256) void k_gemm(const float* __restrict__ H,
                                              const float* __restrict__ W,
                                              const float* __restrict__ dinv,
                                              _Float16* __restrict__ out, int nRows) {
  __shared__ float Wl[BK][NF];       // 16 KB
  __shared__ float Hl[BM][BK + 4];   // stride 36 floats (144 B, 16B-aligned), 9 KB

  const int tid = threadIdx.x;
  const int c4 = (tid & 31) * 4;     // output col base
  const int rg = (tid >> 5) * 8;     // row-group base (8 rows per thread)
  const int rowBase = blockIdx.x * BM;

  float acc[8][4];
#pragma unroll
  for (int j = 0; j < 8; ++j)
#pragma unroll
    for (int c = 0; c < 4; ++c) acc[j][c] = 0.f;

  for (int kc = 0; kc < NF; kc += BK) {
    __syncthreads();   // protect LDS from previous chunk's readers
    // stage W chunk [BK][128] (contiguous copy)
    {
      const float4* src = reinterpret_cast<const float4*>(W + (size_t)kc * NF);
      float4* dst = reinterpret_cast<float4*>(&Wl[0][0]);
      for (int i = tid; i < BK * NF / 4; i += 256) dst[i] = src[i];
    }
    // stage H chunk [BM][BK]
    {
      int r0 = tid >> 3;
      int cs = (tid & 7) * 4;
#pragma unroll
      for (int half = 0; half < 2; ++half) {
        int r = r0 + half * 32;
        int gr = rowBase + r;
        float4 v = make_float4(0.f, 0.f, 0.f, 0.f);
        if (gr < nRows)
          v = *reinterpret_cast<const float4*>(H + (size_t)gr * NF + kc + cs);
        *reinterpret_cast<float4*>(&Hl[r][cs]) = v;
      }
    }
    __syncthreads();

#pragma unroll
    for (int k = 0; k < BK; k += 4) {
      float4 w0 = *reinterpret_cast<float4*>(&Wl[k + 0][c4]);
      float4 w1 = *reinterpret_cast<float4*>(&Wl[k + 1][c4]);
      float4 w2 = *reinterpret_cast<float4*>(&Wl[k + 2][c4]);
      float4 w3 = *reinterpret_cast<float4*>(&Wl[k + 3][c4]);
#pragma unroll
      for (int j = 0; j < 8; ++j) {
        float4 hv = *reinterpret_cast<float4*>(&Hl[rg + j][k]);   // broadcast read
        acc[j][0] = fmaf(hv.x, w0.x, acc[j][0]);
        acc[j][1] = fmaf(hv.x, w0.y, acc[j][1]);
        acc[j][2] = fmaf(hv.x, w0.z, acc[j][2]);
        acc[j][3] = fmaf(hv.x, w0.w, acc[j][3]);
        acc[j][0] = fmaf(hv.y, w1.x, acc[j][0]);
        acc[j][1] = fmaf(hv.y, w1.y, acc[j][1]);
        acc[j][2] = fmaf(hv.y, w1.z, acc[j][2]);
        acc[j][3] = fmaf(hv.y, w1.w, acc[j][3]);
        acc[j][0] = fmaf(hv.z, w2.x, acc[j][0]);
        acc[j][1] = fmaf(hv.z, w2.y, acc[j][1]);
        acc[j][2] = fmaf(hv.z, w2.z, acc[j][2]);
        acc[j][3] = fmaf(hv.z, w2.w, acc[j][3]);
        acc[j][0] = fmaf(hv.w, w3.x, acc[j][0]);
        acc[j][1] = fmaf(hv.w, w3.y, acc[j][1]);
        acc[j][2] = fmaf(hv.w, w3.z, acc[j][2]);
        acc[j][3] = fmaf(hv.w, w3.w, acc[j][3]);
      }
    }
  }

#pragma unroll
  for (int j = 0; j < 8; ++j) {
    int gr = rowBase + rg + j;
    if (gr < nRows) {
      float dv = dinv[gr];
      vhalf4 v;
      v.x = (_Float16)(dv * acc[j][0]);
      v.y = (_Float16)(dv * acc[j][1]);
      v.z = (_Float16)(dv * acc[j][2]);
      v.w = (_Float16)(dv * acc[j][3]);
      *reinterpret_cast<vhalf4*>(out + (size_t)gr * NF + c4) = v;
    }
  }
}

// ---------------------------------------------------------------------------
// Aggregation: h[v] = tanh( dinv[v]*( sum_src tmp'[src] + 2*tmp'[v] ) + b )
// tmp' is fp16, pre-scaled by dinv (see k_gemm). f32 accumulation.
// Half-wave (32 lanes) per node, half4 (8 B) per lane = 256 B/row per instr.
// Edge loop unrolled x8, CSR read as 4-edge int4 nontemporal.
// ---------------------------------------------------------------------------
__device__ __forceinline__ float4 h2f(vhalf4 v) {
  return make_float4((float)v.x, (float)v.y, (float)v.z, (float)v.w);
}
__device__ __forceinline__ float4 add4(float4 a, float4 acc) {
  acc.x += a.x; acc.y += a.y; acc.z += a.z; acc.w += a.w;
  return acc;
}

__global__ __launch_bounds__(256) void k_agg(const _Float16* __restrict__ tmp,
                                             const int* __restrict__ offs,
                                             const int* __restrict__ ends,
                                             const int* __restrict__ csr,
                                             const float* __restrict__ dinv,
                                             const float* __restrict__ bias,
                                             float* __restrict__ hout, int N) {
  int node = (blockIdx.x * 256 + threadIdx.x) >> 5;
  if (node >= N) return;
  int lane = threadIdx.x & 31;

  float dv = dinv[node];

  const vhalf4* t4 = reinterpret_cast<const vhalf4*>(tmp);
  float4 hv = h2f(t4[(size_t)node * 32 + lane]);
  float4 acc = make_float4(2.f * hv.x, 2.f * hv.y, 2.f * hv.z, 2.f * hv.w);

  int s = offs[node], e = ends[node];
  int i = s;

  // align i to 4 so vint4 (4-edge) loads are 16B-aligned
  for (; (i & 3) && i < e; ++i) {
    float4 a = h2f(t4[(size_t)csr[i] * 32 + lane]);
    acc = add4(a, acc);
  }

  const vint4* cp = reinterpret_cast<const vint4*>(csr);
  for (; i + 8 <= e; i += 8) {
    vint4 p0 = __builtin_nontemporal_load(&cp[(i >> 2) + 0]);
    vint4 p1 = __builtin_nontemporal_load(&cp[(i >> 2) + 1]);
    float4 a0 = h2f(t4[(size_t)p0.x * 32 + lane]);
    float4 a1 = h2f(t4[(size_t)p0.y * 32 + lane]);
    float4 a2 = h2f(t4[(size_t)p0.z * 32 + lane]);
    float4 a3 = h2f(t4[(size_t)p0.w * 32 + lane]);
    float4 a4 = h2f(t4[(size_t)p1.x * 32 + lane]);
    float4 a5 = h2f(t4[(size_t)p1.y * 32 + lane]);
    float4 a6 = h2f(t4[(size_t)p1.z * 32 + lane]);
    float4 a7 = h2f(t4[(size_t)p1.w * 32 + lane]);
    acc = add4(a0, acc); acc = add4(a1, acc);
    acc = add4(a2, acc); acc = add4(a3, acc);
    acc = add4(a4, acc); acc = add4(a5, acc);
    acc = add4(a6, acc); acc = add4(a7, acc);
  }
  for (; i + 4 <= e; i += 4) {
    vint4 p = __builtin_nontemporal_load(&cp[i >> 2]);
    float4 a0 = h2f(t4[(size_t)p.x * 32 + lane]);
    float4 a1 = h2f(t4[(size_t)p.y * 32 + lane]);
    float4 a2 = h2f(t4[(size_t)p.z * 32 + lane]);
    float4 a3 = h2f(t4[(size_t)p.w * 32 + lane]);
    acc = add4(a0, acc); acc = add4(a1, acc);
    acc = add4(a2, acc); acc = add4(a3, acc);
  }
  for (; i < e; ++i) {
    float4 a = h2f(t4[(size_t)csr[i] * 32 + lane]);
    acc = add4(a, acc);
  }

  float4 b4 = reinterpret_cast<const float4*>(bias)[lane];
  vfloat4 r;
  r.x = tanhf(fmaf(dv, acc.x, b4.x));
  r.y = tanhf(fmaf(dv, acc.y, b4.y));
  r.z = tanhf(fmaf(dv, acc.z, b4.z));
  r.w = tanhf(fmaf(dv, acc.w, b4.w));
  vfloat4* outp = reinterpret_cast<vfloat4*>(hout) + ((size_t)node * 32 + lane);
  __builtin_nontemporal_store(r, outp);
}

// ---------------------------------------------------------------------------
// Pool (segment max + mean over sorted batch_index) fused with the linear head.
// One block (512 threads = 4 row-stripes of 128 features) per graph.
// ---------------------------------------------------------------------------
__global__ __launch_bounds__(512) void k_pool(const float* __restrict__ h,
                                              const int* __restrict__ batch,
                                              const float* __restrict__ Wout,
                                              const float* __restrict__ bout,
                                              float* __restrict__ out, int N) {
  int g = blockIdx.x;

  // lower_bound(batch, g) and lower_bound(batch, g+1): all threads redundantly
  int lo = 0, hi = N;
  while (lo < hi) { int mid = (lo + hi) >> 1; if (batch[mid] < g) lo = mid + 1; else hi = mid; }
  int s = lo;
  int lo2 = s, hi2 = N;
  while (lo2 < hi2) { int mid = (lo2 + hi2) >> 1; if (batch[mid] < g + 1) lo2 = mid + 1; else hi2 = mid; }
  int e = lo2;

  int f = threadIdx.x & 127;
  int stripe = threadIdx.x >> 7;   // 0..3

  float mx = -INFINITY, sm = 0.f;
  for (int n = s + stripe; n < e; n += 4) {
    float v = h[(size_t)n * NF + f];
    mx = fmaxf(mx, v);
    sm += v;
  }

  __shared__ float smx[4][NF];
  __shared__ float ssm[4][NF];
  smx[stripe][f] = mx;
  ssm[stripe][f] = sm;
  __syncthreads();

  if (stripe == 0) {
    mx = fmaxf(fmaxf(smx[0][f], smx[1][f]), fmaxf(smx[2][f], smx[3][f]));
    sm = ssm[0][f] + ssm[1][f] + ssm[2][f] + ssm[3][f];

    int cnt = e - s;
    float mean = sm / fmaxf((float)cnt, 1.0f);
    if (cnt == 0) mx = 0.f;

    float part = mx * Wout[f] + mean * Wout[NF + f];

    // reduce 128 threads = 2 waves
    for (int o = 32; o > 0; o >>= 1) part += __shfl_down(part, o);
    __shared__ float wsum[2];
    if ((threadIdx.x & 63) == 0) wsum[threadIdx.x >> 6] = part;
    __syncthreads();
    if (threadIdx.x == 0) out[g] = wsum[0] + wsum[1] + bout[0];
  }
}

// ---------------------------------------------------------------------------
// Driver
// ---------------------------------------------------------------------------
extern "C" void kernel_launch(void* const* d_in, const int* in_sizes, int n_in,
                              void* d_out, int out_size, void* d_ws, size_t ws_size,
                              hipStream_t stream) {
  const float* x     = (const float*)d_in[0];
  const int*   eidx  = (const int*)d_in[1];     // [2][E]
  const int*   batch = (const int*)d_in[2];     // [N]
  const float* W0    = (const float*)d_in[3];
  const float* b0    = (const float*)d_in[4];
  const float* Whid  = (const float*)d_in[5];   // [2][128][128]
  const float* bhid  = (const float*)d_in[6];   // [2][128]
  const float* Wout  = (const float*)d_in[7];   // [256]
  const float* bout  = (const float*)d_in[8];   // [1]
  float* out = (float*)d_out;

  const int N = in_sizes[0] / NF;
  const int E = in_sizes[1] / 2;
  const int G = out_size;

  const int* erow = eidx;
  const int* ecol = eidx + E;

  // workspace layout (256B aligned)
  size_t off = 0;
  auto alloc = [&](size_t bytes) -> void* {
    void* p = (char*)d_ws + off;
    off += (bytes + 255) & ~(size_t)255;
    return p;
  };
  int*      cnt    = (int*)alloc((size_t)N * 4);
  float*    dinv   = (float*)alloc((size_t)N * 4);
  int*      offs   = (int*)alloc((size_t)N * 4);
  int*      cursor = (int*)alloc((size_t)N * 4);
  int*      total  = (int*)alloc(16);
  int*      csr    = (int*)alloc((size_t)E * 4);
  _Float16* tmp    = (_Float16*)alloc((size_t)N * NF * 2);
  float*    h      = (float*)alloc((size_t)N * NF * 4);
  (void)ws_size;

  (void)hipMemsetAsync(cnt, 0, (size_t)N * 4, stream);
  (void)hipMemsetAsync(total, 0, 16, stream);

  int gE = (E + 255) / 256;
  int gN = (N + 255) / 256;

  k_count<<<gE, 256, 0, stream>>>(ecol, cnt, E);
  k_nodeinit<<<gN, 256, 0, stream>>>(cnt, dinv, offs, cursor, total, N);
  k_fill<<<gE, 256, 0, stream>>>(erow, ecol, cursor, csr, E);

  const int gemmGrid = (N + BM - 1) / BM;
  const int aggGrid = (N + 7) / 8;          // 8 nodes (half-waves) per 256-thr block

  // layer 0: x -> tmp -> h
  k_gemm<<<gemmGrid, 256, 0, stream>>>(x, W0, dinv, tmp, N);
  k_agg<<<aggGrid, 256, 0, stream>>>(tmp, offs, cursor, csr, dinv, b0, h, N);
  // layer 1
  k_gemm<<<gemmGrid, 256, 0, stream>>>(h, Whid, dinv, tmp, N);
  k_agg<<<aggGrid, 256, 0, stream>>>(tmp, offs, cursor, csr, dinv, bhid, h, N);
  // layer 2
  k_gemm<<<gemmGrid, 256, 0, stream>>>(h, Whid + 128 * 128, dinv, tmp, N);
  k_agg<<<aggGrid, 256, 0, stream>>>(tmp, offs, cursor, csr, dinv, bhid + NF, h, N);

  // pooling + head
  k_pool<<<G, 512, 0, stream>>>(h, batch, Wout, bout, out, N);
}

// Round 7
// 823.906 us; speedup vs baseline: 1.1775x; 1.1775x over previous
//
#include <hip/hip_runtime.h>
#include <math.h>

#define NF 128       // feature width (both in and out of every layer)
#define NPART 8      // one partition per XCD (blockIdx % 8 -> XCD, round-robin)
#define SCAN_CHUNK 1024

typedef int      vint4   __attribute__((ext_vector_type(4)));
typedef float    vfloat4 __attribute__((ext_vector_type(4)));
typedef _Float16 vhalf4  __attribute__((ext_vector_type(4)));

// ---------------------------------------------------------------------------
// XCD-partitioned degree count: partition p owns node range [lo,hi).
// Each partition scans the WHOLE col array (sequential int4 reads, L3-hit
// after first pass) and counts only its own nodes -> cnt atomics stay in
// one XCD's L2 region.
// ---------------------------------------------------------------------------
__global__ __launch_bounds__(256) void k_count(const int* __restrict__ col,
                                               int* __restrict__ cnt, int E, int N) {
  int part = blockIdx.x & (NPART - 1);
  int lo = (int)((long)part * N / NPART);
  int hi = (int)((long)(part + 1) * N / NPART);
  int bip = blockIdx.x >> 3;          // block index within partition
  int nbp = gridDim.x >> 3;           // blocks per partition
  int stride = nbp * 256;
  int t = bip * 256 + threadIdx.x;

  const vint4* c4 = reinterpret_cast<const vint4*>(col);
  int E4 = E >> 2;
  for (int i = t; i < E4; i += stride) {
    vint4 c = c4[i];
    if (c.x >= lo && c.x < hi) atomicAdd(&cnt[c.x], 1);
    if (c.y >= lo && c.y < hi) atomicAdd(&cnt[c.y], 1);
    if (c.z >= lo && c.z < hi) atomicAdd(&cnt[c.z], 1);
    if (c.w >= lo && c.w < hi) atomicAdd(&cnt[c.w], 1);
  }
  // tail (E not multiple of 4)
  for (int i = (E4 << 2) + t; i < E; i += stride) {
    int c = col[i];
    if (c >= lo && c < hi) atomicAdd(&cnt[c], 1);
  }
}

// ---------------------------------------------------------------------------
// Ordered exclusive prefix-sum of cnt -> offs (so each partition's csr slice
// is contiguous and stays in its own L2). 3 tiny kernels over 400 KB.
// k_scanB requires nChunks <= 128 (N <= 131072).
// ---------------------------------------------------------------------------
__global__ __launch_bounds__(256) void k_scanA(const int* __restrict__ cnt,
                                               int* __restrict__ chunkTot, int N) {
  int c0 = blockIdx.x * SCAN_CHUNK + threadIdx.x * 4;
  int s = 0;
#pragma unroll
  for (int j = 0; j < 4; ++j) {
    int idx = c0 + j;
    if (idx < N) s += cnt[idx];
  }
  __shared__ int red[256];
  red[threadIdx.x] = s;
  __syncthreads();
  for (int o = 128; o > 0; o >>= 1) {
    if (threadIdx.x < o) red[threadIdx.x] += red[threadIdx.x + o];
    __syncthreads();
  }
  if (threadIdx.x == 0) chunkTot[blockIdx.x] = red[0];
}

__global__ __launch_bounds__(128) void k_scanB(const int* __restrict__ chunkTot,
                                               int* __restrict__ chunkOff, int nChunks) {
  __shared__ int buf[128];
  int t = threadIdx.x;
  int v = (t < nChunks) ? chunkTot[t] : 0;
  buf[t] = v;
  __syncthreads();
  for (int o = 1; o < 128; o <<= 1) {
    int x = buf[t];
    if (t >= o) x += buf[t - o];
    __syncthreads();
    buf[t] = x;
    __syncthreads();
  }
  if (t < nChunks) chunkOff[t] = buf[t] - v;   // exclusive
}

__global__ __launch_bounds__(256) void k_scanC(const int* __restrict__ cnt,
                                               const int* __restrict__ chunkOff,
                                               int* __restrict__ offs,
                                               int* __restrict__ cursor,
                                               float* __restrict__ dinv, int N) {
  int t = threadIdx.x;
  int c0 = blockIdx.x * SCAN_CHUNK + t * 4;
  int v[4];
  int s = 0;
#pragma unroll
  for (int j = 0; j < 4; ++j) {
    int idx = c0 + j;
    v[j] = (idx < N) ? cnt[idx] : 0;
    s += v[j];
  }
  __shared__ int buf[256];
  buf[t] = s;
  __syncthreads();
  for (int o = 1; o < 256; o <<= 1) {
    int x = buf[t];
    if (t >= o) x += buf[t - o];
    __syncthreads();
    buf[t] = x;
    __syncthreads();
  }
  int excl = buf[t] - s + chunkOff[blockIdx.x];
#pragma unroll
  for (int j = 0; j < 4; ++j) {
    int idx = c0 + j;
    if (idx < N) {
      offs[idx] = excl;
      cursor[idx] = excl;
      dinv[idx] = rsqrtf((float)v[j] + 2.0f);   // deg + FILL(2.0) self-loop
      excl += v[j];
    }
  }
}

// ---------------------------------------------------------------------------
// XCD-partitioned CSR fill. Partition p writes only csr[offs[lo]..offs[hi])
// -- a contiguous ~E/8*4 B slice that fits its L2, so lines fill completely
// and write back once (round-6 profile: unpartitioned scatter caused one
// full-line HBM eviction per edge, 194 MB writes).
// CSR stores ONLY the src index (weight folded into GEMM epilogue).
// ---------------------------------------------------------------------------
__global__ __launch_bounds__(256) void k_fill(const int* __restrict__ row,
                                              const int* __restrict__ col,
                                              int* __restrict__ cursor,
                                              int* __restrict__ csr, int E, int N) {
  int part = blockIdx.x & (NPART - 1);
  int lo = (int)((long)part * N / NPART);
  int hi = (int)((long)(part + 1) * N / NPART);
  int bip = blockIdx.x >> 3;
  int nbp = gridDim.x >> 3;
  int stride = nbp * 256;
  int t = bip * 256 + threadIdx.x;

  const vint4* c4 = reinterpret_cast<const vint4*>(col);
  const vint4* r4 = reinterpret_cast<const vint4*>(row);
  int E4 = E >> 2;
  for (int i = t; i < E4; i += stride) {
    vint4 c = c4[i];
    vint4 r = r4[i];
    if (c.x >= lo && c.x < hi) csr[atomicAdd(&cursor[c.x], 1)] = r.x;
    if (c.y >= lo && c.y < hi) csr[atomicAdd(&cursor[c.y], 1)] = r.y;
    if (c.z >= lo && c.z < hi) csr[atomicAdd(&cursor[c.z], 1)] = r.z;
    if (c.w >= lo && c.w < hi) csr[atomicAdd(&cursor[c.w], 1)] = r.w;
  }
  for (int i = (E4 << 2) + t; i < E; i += stride) {
    int c = col[i];
    if (c >= lo && c < hi) csr[atomicAdd(&cursor[c], 1)] = row[i];
  }
}

// ---------------------------------------------------------------------------
// GEMM: out[N,128] = dinv[row] * (H[N,128] @ W[128,128])  (f32 FMA, fp16 out)
// Tile 64 rows x 128 cols per block, BK=32 K-chunks.
// 256 threads; thread = 8 rows x 4 cols.
// ---------------------------------------------------------------------------
#define BM 64
#define BK 32
__global__ __launch_bounds__(256) void k_gemm(const float* __restrict__ H,
                                              const float* __restrict__ W,
                                              const float* __restrict__ dinv,
                                              _Float16* __restrict__ out, int nRows) {
  __shared__ float Wl[BK][NF];       // 16 KB
  __shared__ float Hl[BM][BK + 4];   // stride 36 floats (144 B, 16B-aligned), 9 KB

  const int tid = threadIdx.x;
  const int c4 = (tid & 31) * 4;     // output col base
  const int rg = (tid >> 5) * 8;     // row-group base (8 rows per thread)
  const int rowBase = blockIdx.x * BM;

  float acc[8][4];
#pragma unroll
  for (int j = 0; j < 8; ++j)
#pragma unroll
    for (int c = 0; c < 4; ++c) acc[j][c] = 0.f;

  for (int kc = 0; kc < NF; kc += BK) {
    __syncthreads();   // protect LDS from previous chunk's readers
    // stage W chunk [BK][128] (contiguous copy)
    {
      const float4* src = reinterpret_cast<const float4*>(W + (size_t)kc * NF);
      float4* dst = reinterpret_cast<float4*>(&Wl[0][0]);
      for (int i = tid; i < BK * NF / 4; i += 256) dst[i] = src[i];
    }
    // stage H chunk [BM][BK]
    {
      int r0 = tid >> 3;
      int cs = (tid & 7) * 4;
#pragma unroll
      for (int half = 0; half < 2; ++half) {
        int r = r0 + half * 32;
        int gr = rowBase + r;
        float4 v = make_float4(0.f, 0.f, 0.f, 0.f);
        if (gr < nRows)
          v = *reinterpret_cast<const float4*>(H + (size_t)gr * NF + kc + cs);
        *reinterpret_cast<float4*>(&Hl[r][cs]) = v;
      }
    }
    __syncthreads();

#pragma unroll
    for (int k = 0; k < BK; k += 4) {
      float4 w0 = *reinterpret_cast<float4*>(&Wl[k + 0][c4]);
      float4 w1 = *reinterpret_cast<float4*>(&Wl[k + 1][c4]);
      float4 w2 = *reinterpret_cast<float4*>(&Wl[k + 2][c4]);
      float4 w3 = *reinterpret_cast<float4*>(&Wl[k + 3][c4]);
#pragma unroll
      for (int j = 0; j < 8; ++j) {
        float4 hv = *reinterpret_cast<float4*>(&Hl[rg + j][k]);   // broadcast read
        acc[j][0] = fmaf(hv.x, w0.x, acc[j][0]);
        acc[j][1] = fmaf(hv.x, w0.y, acc[j][1]);
        acc[j][2] = fmaf(hv.x, w0.z, acc[j][2]);
        acc[j][3] = fmaf(hv.x, w0.w, acc[j][3]);
        acc[j][0] = fmaf(hv.y, w1.x, acc[j][0]);
        acc[j][1] = fmaf(hv.y, w1.y, acc[j][1]);
        acc[j][2] = fmaf(hv.y, w1.z, acc[j][2]);
        acc[j][3] = fmaf(hv.y, w1.w, acc[j][3]);
        acc[j][0] = fmaf(hv.z, w2.x, acc[j][0]);
        acc[j][1] = fmaf(hv.z, w2.y, acc[j][1]);
        acc[j][2] = fmaf(hv.z, w2.z, acc[j][2]);
        acc[j][3] = fmaf(hv.z, w2.w, acc[j][3]);
        acc[j][0] = fmaf(hv.w, w3.x, acc[j][0]);
        acc[j][1] = fmaf(hv.w, w3.y, acc[j][1]);
        acc[j][2] = fmaf(hv.w, w3.z, acc[j][2]);
        acc[j][3] = fmaf(hv.w, w3.w, acc[j][3]);
      }
    }
  }

#pragma unroll
  for (int j = 0; j < 8; ++j) {
    int gr = rowBase + rg + j;
    if (gr < nRows) {
      float dv = dinv[gr];
      vhalf4 v;
      v.x = (_Float16)(dv * acc[j][0]);
      v.y = (_Float16)(dv * acc[j][1]);
      v.z = (_Float16)(dv * acc[j][2]);
      v.w = (_Float16)(dv * acc[j][3]);
      *reinterpret_cast<vhalf4*>(out + (size_t)gr * NF + c4) = v;
    }
  }
}

// ---------------------------------------------------------------------------
// Aggregation: h[v] = tanh( dinv[v]*( sum_src tmp'[src] + 2*tmp'[v] ) + b )
// tmp' is fp16, pre-scaled by dinv (see k_gemm). f32 accumulation.
// Half-wave (32 lanes) per node, half4 (8 B) per lane = 256 B/row per instr.
// Edge loop unrolled x8, CSR read as 4-edge int4 nontemporal.
// ---------------------------------------------------------------------------
__device__ __forceinline__ float4 h2f(vhalf4 v) {
  return make_float4((float)v.x, (float)v.y, (float)v.z, (float)v.w);
}
__device__ __forceinline__ float4 add4(float4 a, float4 acc) {
  acc.x += a.x; acc.y += a.y; acc.z += a.z; acc.w += a.w;
  return acc;
}

__global__ __launch_bounds__(256) void k_agg(const _Float16* __restrict__ tmp,
                                             const int* __restrict__ offs,
                                             const int* __restrict__ ends,
                                             const int* __restrict__ csr,
                                             const float* __restrict__ dinv,
                                             const float* __restrict__ bias,
                                             float* __restrict__ hout, int N) {
  int node = (blockIdx.x * 256 + threadIdx.x) >> 5;
  if (node >= N) return;
  int lane = threadIdx.x & 31;

  float dv = dinv[node];

  const vhalf4* t4 = reinterpret_cast<const vhalf4*>(tmp);
  float4 hv = h2f(t4[(size_t)node * 32 + lane]);
  float4 acc = make_float4(2.f * hv.x, 2.f * hv.y, 2.f * hv.z, 2.f * hv.w);

  int s = offs[node], e = ends[node];
  int i = s;

  // align i to 4 so vint4 (4-edge) loads are 16B-aligned
  for (; (i & 3) && i < e; ++i) {
    float4 a = h2f(t4[(size_t)csr[i] * 32 + lane]);
    acc = add4(a, acc);
  }

  const vint4* cp = reinterpret_cast<const vint4*>(csr);
  for (; i + 8 <= e; i += 8) {
    vint4 p0 = __builtin_nontemporal_load(&cp[(i >> 2) + 0]);
    vint4 p1 = __builtin_nontemporal_load(&cp[(i >> 2) + 1]);
    float4 a0 = h2f(t4[(size_t)p0.x * 32 + lane]);
    float4 a1 = h2f(t4[(size_t)p0.y * 32 + lane]);
    float4 a2 = h2f(t4[(size_t)p0.z * 32 + lane]);
    float4 a3 = h2f(t4[(size_t)p0.w * 32 + lane]);
    float4 a4 = h2f(t4[(size_t)p1.x * 32 + lane]);
    float4 a5 = h2f(t4[(size_t)p1.y * 32 + lane]);
    float4 a6 = h2f(t4[(size_t)p1.z * 32 + lane]);
    float4 a7 = h2f(t4[(size_t)p1.w * 32 + lane]);
    acc = add4(a0, acc); acc = add4(a1, acc);
    acc = add4(a2, acc); acc = add4(a3, acc);
    acc = add4(a4, acc); acc = add4(a5, acc);
    acc = add4(a6, acc); acc = add4(a7, acc);
  }
  for (; i + 4 <= e; i += 4) {
    vint4 p = __builtin_nontemporal_load(&cp[i >> 2]);
    float4 a0 = h2f(t4[(size_t)p.x * 32 + lane]);
    float4 a1 = h2f(t4[(size_t)p.y * 32 + lane]);
    float4 a2 = h2f(t4[(size_t)p.z * 32 + lane]);
    float4 a3 = h2f(t4[(size_t)p.w * 32 + lane]);
    acc = add4(a0, acc); acc = add4(a1, acc);
    acc = add4(a2, acc); acc = add4(a3, acc);
  }
  for (; i < e; ++i) {
    float4 a = h2f(t4[(size_t)csr[i] * 32 + lane]);
    acc = add4(a, acc);
  }

  float4 b4 = reinterpret_cast<const float4*>(bias)[lane];
  vfloat4 r;
  r.x = tanhf(fmaf(dv, acc.x, b4.x));
  r.y = tanhf(fmaf(dv, acc.y, b4.y));
  r.z = tanhf(fmaf(dv, acc.z, b4.z));
  r.w = tanhf(fmaf(dv, acc.w, b4.w));
  vfloat4* outp = reinterpret_cast<vfloat4*>(hout) + ((size_t)node * 32 + lane);
  __builtin_nontemporal_store(r, outp);
}

// ---------------------------------------------------------------------------
// Pool (segment max + mean over sorted batch_index) fused with the linear head.
// One block (512 threads = 4 row-stripes of 128 features) per graph.
// ---------------------------------------------------------------------------
__global__ __launch_bounds__(512) void k_pool(const float* __restrict__ h,
                                              const int* __restrict__ batch,
                                              const float* __restrict__ Wout,
                                              const float* __restrict__ bout,
                                              float* __restrict__ out, int N) {
  int g = blockIdx.x;

  // lower_bound(batch, g) and lower_bound(batch, g+1): all threads redundantly
  int lo = 0, hi = N;
  while (lo < hi) { int mid = (lo + hi) >> 1; if (batch[mid] < g) lo = mid + 1; else hi = mid; }
  int s = lo;
  int lo2 = s, hi2 = N;
  while (lo2 < hi2) { int mid = (lo2 + hi2) >> 1; if (batch[mid] < g + 1) lo2 = mid + 1; else hi2 = mid; }
  int e = lo2;

  int f = threadIdx.x & 127;
  int stripe = threadIdx.x >> 7;   // 0..3

  float mx = -INFINITY, sm = 0.f;
  for (int n = s + stripe; n < e; n += 4) {
    float v = h[(size_t)n * NF + f];
    mx = fmaxf(mx, v);
    sm += v;
  }

  __shared__ float smx[4][NF];
  __shared__ float ssm[4][NF];
  smx[stripe][f] = mx;
  ssm[stripe][f] = sm;
  __syncthreads();

  if (stripe == 0) {
    mx = fmaxf(fmaxf(smx[0][f], smx[1][f]), fmaxf(smx[2][f], smx[3][f]));
    sm = ssm[0][f] + ssm[1][f] + ssm[2][f] + ssm[3][f];

    int cnt = e - s;
    float mean = sm / fmaxf((float)cnt, 1.0f);
    if (cnt == 0) mx = 0.f;

    float part = mx * Wout[f] + mean * Wout[NF + f];

    // reduce 128 threads = 2 waves
    for (int o = 32; o > 0; o >>= 1) part += __shfl_down(part, o);
    __shared__ float wsum[2];
    if ((threadIdx.x & 63) == 0) wsum[threadIdx.x >> 6] = part;
    __syncthreads();
    if (threadIdx.x == 0) out[g] = wsum[0] + wsum[1] + bout[0];
  }
}

// ---------------------------------------------------------------------------
// Driver
// ---------------------------------------------------------------------------
extern "C" void kernel_launch(void* const* d_in, const int* in_sizes, int n_in,
                              void* d_out, int out_size, void* d_ws, size_t ws_size,
                              hipStream_t stream) {
  const float* x     = (const float*)d_in[0];
  const int*   eidx  = (const int*)d_in[1];     // [2][E]
  const int*   batch = (const int*)d_in[2];     // [N]
  const float* W0    = (const float*)d_in[3];
  const float* b0    = (const float*)d_in[4];
  const float* Whid  = (const float*)d_in[5];   // [2][128][128]
  const float* bhid  = (const float*)d_in[6];   // [2][128]
  const float* Wout  = (const float*)d_in[7];   // [256]
  const float* bout  = (const float*)d_in[8];   // [1]
  float* out = (float*)d_out;

  const int N = in_sizes[0] / NF;
  const int E = in_sizes[1] / 2;
  const int G = out_size;

  const int* erow = eidx;
  const int* ecol = eidx + E;

  // workspace layout (256B aligned)
  size_t off = 0;
  auto alloc = [&](size_t bytes) -> void* {
    void* p = (char*)d_ws + off;
    off += (bytes + 255) & ~(size_t)255;
    return p;
  };
  int*      cnt      = (int*)alloc((size_t)N * 4);
  float*    dinv     = (float*)alloc((size_t)N * 4);
  int*      offs     = (int*)alloc((size_t)N * 4);
  int*      cursor   = (int*)alloc((size_t)N * 4);
  int*      chunkTot = (int*)alloc(1024);
  int*      chunkOff = (int*)alloc(1024);
  int*      csr      = (int*)alloc((size_t)E * 4);
  _Float16* tmp      = (_Float16*)alloc((size_t)N * NF * 2);
  float*    h        = (float*)alloc((size_t)N * NF * 4);
  (void)ws_size;

  (void)hipMemsetAsync(cnt, 0, (size_t)N * 4, stream);

  const int nChunks = (N + SCAN_CHUNK - 1) / SCAN_CHUNK;   // 98 for N=100k (<=128)
  const int partGrid = 128 * NPART;                        // 128 blocks per XCD

  k_count<<<partGrid, 256, 0, stream>>>(ecol, cnt, E, N);
  k_scanA<<<nChunks, 256, 0, stream>>>(cnt, chunkTot, N);
  k_scanB<<<1, 128, 0, stream>>>(chunkTot, chunkOff, nChunks);
  k_scanC<<<nChunks, 256, 0, stream>>>(cnt, chunkOff, offs, cursor, dinv, N);
  k_fill<<<partGrid, 256, 0, stream>>>(erow, ecol, cursor, csr, E, N);

  const int gemmGrid = (N + BM - 1) / BM;
  const int aggGrid = (N + 7) / 8;          // 8 nodes (half-waves) per 256-thr block

  // layer 0: x -> tmp -> h
  k_gemm<<<gemmGrid, 256, 0, stream>>>(x, W0, dinv, tmp, N);
  k_agg<<<aggGrid, 256, 0, stream>>>(tmp, offs, cursor, csr, dinv, b0, h, N);
  // layer 1
  k_gemm<<<gemmGrid, 256, 0, stream>>>(h, Whid, dinv, tmp, N);
  k_agg<<<aggGrid, 256, 0, stream>>>(tmp, offs, cursor, csr, dinv, bhid, h, N);
  // layer 2
  k_gemm<<<gemmGrid, 256, 0, stream>>>(h, Whid + 128 * 128, dinv, tmp, N);
  k_agg<<<aggGrid, 256, 0, stream>>>(tmp, offs, cursor, csr, dinv, bhid + NF, h, N);

  // pooling + head
  k_pool<<<G, 512, 0, stream>>>(h, batch, Wout, bout, out, N);
}